// Round 4
// baseline (73.251 us; speedup 1.0000x reference)
//
#include <hip/hip_runtime.h>
#include <math.h>

#define BB 512
#define DD 128
#define KK 8
#define BOUNDARY 4

// ---------------- workspace layout (bytes) ----------------
// partS : 0    .. 2048   (512 float)  per-column loss partial sum
// partC : 2048 .. 4096   (512 int)    per-column hinge count
// Written unconditionally -> no memset needed. NO device-scope atomics/fences
// (prior session: single-kernel finalize costs 40-60 us cross-XCD tail).
//
// Round history: R1 3-kernel split +2.8us (extra graph node). R2 2-launch
// 71.5. R3 2-row MLP -0.5us only -> distance phase is L2-TRAFFIC-bound
// (~512 KB/CU at ~56 B/cyc/CU ~= 3.9us floor), not latency-bound.
// R4 (this file): TWO COLUMNS PER BLOCK, 256 blocks.
//  * every xr row load serves 2 distance columns -> per-CU L2 traffic
//    halves (1 block/CU x 256 KB), distance floor ~2us — the round-1 traffic
//    fix without the extra launch that killed it.
//  * top-k extraction runs 2 columns in PARALLEL (wave0=colA, wave1=colB,
//    wave2=histogram) instead of 1 wave active / 7 idle.
//  * per-column arithmetic copied verbatim from the passing R3 kernel ->
//    bitwise-identical distances + selections (no tie-semantics risk).
//
// Algebraic facts exploited (boundary = int(512/128) = 4):
//  * anchor rows belong to classes with <= 3 members, so the positive top-8
//    selects ALL same-class rows: mask_ap[i][j] == anchors[i] & tgt[j]==tgt[i] & i!=j.
//  * block owning column k: its neg top-8 rows r are exactly the (i=r, k)
//    entries of mask_an, and d[r,k] = -s_vn[r] (selected negs are always
//    different-class; s_vn holds -d).
//  * the diagonal is never consumed (neg-masked; positives exclude j==r).
//  * the <= 16 positive distances d[r,j] per column are recomputed directly
//    from x (one 128-dim dot each) — hinge values only, not selections.

__global__ __launch_bounds__(512, 2) void fused2_kernel(
    const float* __restrict__ x, const int* __restrict__ tgt,
    float* __restrict__ partS, int* __restrict__ partC)
{
    __shared__ float4 xiA[DD / 4], xiB[DD / 4];
    __shared__ float s_vnA[BB], s_vnB[BB];   // -d per column, -inf same-class
    __shared__ float s_sq[BB];               // squared norms (row property)
    __shared__ int   s_tgt[BB];
    __shared__ int   s_cnt[128];             // class histogram
    __shared__ int   s_selA[KK], s_selB[KK]; // selected neg rows, -1 invalid
    __shared__ int   s_prA[16], s_pjA[16], s_prB[16], s_pjB[16];
    __shared__ int   s_npA, s_npB;

    const int cA = blockIdx.x * 2, cB = cA + 1;
    const int t = threadIdx.x;               // 0..511
    if (t < DD / 4)             xiA[t]      = ((const float4*)(x + cA * DD))[t];
    else if (t < DD / 2)        xiB[t - 32] = ((const float4*)(x + cB * DD))[t - 32];
    if (t < 128) s_cnt[t] = 0;
    if (t == 0) { s_npA = 0; s_npB = 0; }
    s_tgt[t] = tgt[t];
    __syncthreads();
    const int tkA = s_tgt[cA], tkB = s_tgt[cB];

    // center squared norms (same summation order as the per-column original)
    float sqkA, sqkB;
    {
        float z0 = 0.f, z1 = 0.f, z2 = 0.f, z3 = 0.f;
        for (int c = 0; c < DD / 4; ++c) {
            float4 a = xiA[c];
            z0 += a.x * a.x; z1 += a.y * a.y; z2 += a.z * a.z; z3 += a.w * a.w;
        }
        sqkA = (z0 + z1) + (z2 + z3);
    }
    {
        float z0 = 0.f, z1 = 0.f, z2 = 0.f, z3 = 0.f;
        for (int c = 0; c < DD / 4; ++c) {
            float4 a = xiB[c];
            z0 += a.x * a.x; z1 += a.y * a.y; z2 += a.z * a.z; z3 += a.w * a.w;
        }
        sqkB = (z0 + z1) + (z2 + z3);
    }

    // distance loop: 8 lanes per row (coalesced 128-B segments), 2 rows/pass,
    // each xr load feeds BOTH columns. g = t>>3 (0..63), sub = t&7.
    {
        int g = t >> 3, sub = t & 7;
        for (int pass = 0; pass < 4; ++pass) {
            int r0 = pass * 128 + g;
            int r1 = r0 + 64;
            const float4* xr0 = (const float4*)(x + r0 * DD);
            const float4* xr1 = (const float4*)(x + r1 * DD);
            float4 aA0 = xiA[sub], aA1 = xiA[sub + 8], aA2 = xiA[sub + 16], aA3 = xiA[sub + 24];
            float4 aB0 = xiB[sub], aB1 = xiB[sub + 8], aB2 = xiB[sub + 16], aB3 = xiB[sub + 24];
            float4 p0 = xr0[sub], p1 = xr0[sub + 8], p2 = xr0[sub + 16], p3 = xr0[sub + 24];
            float4 q0 = xr1[sub], q1 = xr1[sub + 8], q2 = xr1[sub + 16], q3 = xr1[sub + 24];

            // row r0
            float dA0 = aA0.x*p0.x + aA0.y*p0.y + aA0.z*p0.z + aA0.w*p0.w;
            float dA1 = aA1.x*p1.x + aA1.y*p1.y + aA1.z*p1.z + aA1.w*p1.w;
            float dA2 = aA2.x*p2.x + aA2.y*p2.y + aA2.z*p2.z + aA2.w*p2.w;
            float dA3 = aA3.x*p3.x + aA3.y*p3.y + aA3.z*p3.z + aA3.w*p3.w;
            float bA0 = aB0.x*p0.x + aB0.y*p0.y + aB0.z*p0.z + aB0.w*p0.w;
            float bA1 = aB1.x*p1.x + aB1.y*p1.y + aB1.z*p1.z + aB1.w*p1.w;
            float bA2 = aB2.x*p2.x + aB2.y*p2.y + aB2.z*p2.z + aB2.w*p2.w;
            float bA3 = aB3.x*p3.x + aB3.y*p3.y + aB3.z*p3.z + aB3.w*p3.w;
            float sA0 = p0.x*p0.x + p0.y*p0.y + p0.z*p0.z + p0.w*p0.w;
            float sA1 = p1.x*p1.x + p1.y*p1.y + p1.z*p1.z + p1.w*p1.w;
            float sA2 = p2.x*p2.x + p2.y*p2.y + p2.z*p2.z + p2.w*p2.w;
            float sA3 = p3.x*p3.x + p3.y*p3.y + p3.z*p3.z + p3.w*p3.w;
            // row r1
            float dB0 = aA0.x*q0.x + aA0.y*q0.y + aA0.z*q0.z + aA0.w*q0.w;
            float dB1 = aA1.x*q1.x + aA1.y*q1.y + aA1.z*q1.z + aA1.w*q1.w;
            float dB2 = aA2.x*q2.x + aA2.y*q2.y + aA2.z*q2.z + aA2.w*q2.w;
            float dB3 = aA3.x*q3.x + aA3.y*q3.y + aA3.z*q3.z + aA3.w*q3.w;
            float bB0 = aB0.x*q0.x + aB0.y*q0.y + aB0.z*q0.z + aB0.w*q0.w;
            float bB1 = aB1.x*q1.x + aB1.y*q1.y + aB1.z*q1.z + aB1.w*q1.w;
            float bB2 = aB2.x*q2.x + aB2.y*q2.y + aB2.z*q2.z + aB2.w*q2.w;
            float bB3 = aB3.x*q3.x + aB3.y*q3.y + aB3.z*q3.z + aB3.w*q3.w;
            float sB0 = q0.x*q0.x + q0.y*q0.y + q0.z*q0.z + q0.w*q0.w;
            float sB1 = q1.x*q1.x + q1.y*q1.y + q1.z*q1.z + q1.w*q1.w;
            float sB2 = q2.x*q2.x + q2.y*q2.y + q2.z*q2.z + q2.w*q2.w;
            float sB3 = q3.x*q3.x + q3.y*q3.y + q3.z*q3.z + q3.w*q3.w;

            float dotA0 = (dA0 + dA1) + (dA2 + dA3);  // row r0 vs center A
            float dotB0 = (bA0 + bA1) + (bA2 + bA3);  // row r0 vs center B
            float sq0   = (sA0 + sA1) + (sA2 + sA3);
            float dotA1 = (dB0 + dB1) + (dB2 + dB3);  // row r1 vs center A
            float dotB1 = (bB0 + bB1) + (bB2 + bB3);  // row r1 vs center B
            float sq1   = (sB0 + sB1) + (sB2 + sB3);
            for (int off = 4; off > 0; off >>= 1) {
                dotA0 += __shfl_down(dotA0, off, 8);
                dotB0 += __shfl_down(dotB0, off, 8);
                sq0   += __shfl_down(sq0,   off, 8);
                dotA1 += __shfl_down(dotA1, off, 8);
                dotB1 += __shfl_down(dotB1, off, 8);
                sq1   += __shfl_down(sq1,   off, 8);
            }
            if (sub == 0) {
                s_sq[r0] = sq0;
                s_sq[r1] = sq1;
                float qA0 = fmaxf((sqkA + sq0) - 2.f * dotA0, 0.f);
                s_vnA[r0] = (s_tgt[r0] == tkA) ? -INFINITY : -((qA0 == 0.f) ? 0.f : sqrtf(qA0));
                float qB0 = fmaxf((sqkB + sq0) - 2.f * dotB0, 0.f);
                s_vnB[r0] = (s_tgt[r0] == tkB) ? -INFINITY : -((qB0 == 0.f) ? 0.f : sqrtf(qB0));
                float qA1 = fmaxf((sqkA + sq1) - 2.f * dotA1, 0.f);
                s_vnA[r1] = (s_tgt[r1] == tkA) ? -INFINITY : -((qA1 == 0.f) ? 0.f : sqrtf(qA1));
                float qB1 = fmaxf((sqkB + sq1) - 2.f * dotB1, 0.f);
                s_vnB[r1] = (s_tgt[r1] == tkB) ? -INFINITY : -((qB1 == 0.f) ? 0.f : sqrtf(qB1));
            }
        }
    }
    __syncthreads();

    const int wave = t >> 6, lane = t & 63;
    if (wave == 0) {
        // neg top-8 column A (lax.top_k: desc value, asc index on ties).
        // Candidates in VGPRs; predicated pop (no scratch demotion).
        float v[8];
#pragma unroll
        for (int q = 0; q < 8; ++q) v[q] = s_vnA[q * 64 + lane];
        for (int pass = 0; pass < KK; ++pass) {
            float bv = -INFINITY; int bq = -1;
#pragma unroll
            for (int q = 0; q < 8; ++q)
                if (v[q] > bv) { bv = v[q]; bq = q; }   // strict > keeps lowest q
            int bi = (bq >= 0) ? (bq * 64 + lane) : (1 << 30);
            for (int off = 32; off > 0; off >>= 1) {
                float ov = __shfl_down(bv, off);
                int   oi = __shfl_down(bi, off);
                if (ov > bv || (ov == bv && oi < bi)) { bv = ov; bi = oi; }
            }
            bv = __shfl(bv, 0); bi = __shfl(bi, 0);
            if (lane == 0) s_selA[pass] = (bv == -INFINITY) ? -1 : bi;
            const int  popq = bi >> 6;
            const bool mine = ((bi & 63) == lane);
#pragma unroll
            for (int q = 0; q < 8; ++q)
                if (mine && q == popq) v[q] = -INFINITY;
        }
    } else if (wave == 1) {
        // neg top-8 column B (identical logic)
        float v[8];
#pragma unroll
        for (int q = 0; q < 8; ++q) v[q] = s_vnB[q * 64 + lane];
        for (int pass = 0; pass < KK; ++pass) {
            float bv = -INFINITY; int bq = -1;
#pragma unroll
            for (int q = 0; q < 8; ++q)
                if (v[q] > bv) { bv = v[q]; bq = q; }
            int bi = (bq >= 0) ? (bq * 64 + lane) : (1 << 30);
            for (int off = 32; off > 0; off >>= 1) {
                float ov = __shfl_down(bv, off);
                int   oi = __shfl_down(bi, off);
                if (ov > bv || (ov == bv && oi < bi)) { bv = ov; bi = oi; }
            }
            bv = __shfl(bv, 0); bi = __shfl(bi, 0);
            if (lane == 0) s_selB[pass] = (bv == -INFINITY) ? -1 : bi;
            const int  popq = bi >> 6;
            const bool mine = ((bi & 63) == lane);
#pragma unroll
            for (int q = 0; q < 8; ++q)
                if (mine && q == popq) v[q] = -INFINITY;
        }
    } else if (wave == 2) {
        // class histogram (includes self-counts)
#pragma unroll
        for (int q = 0; q < 8; ++q) atomicAdd(&s_cnt[s_tgt[q * 64 + lane]], 1);
    }
    __syncthreads();

    // collect (anchor r, positive j) pairs: wave w owns top-k slot w of BOTH
    // columns (each scan = 8 iters over 64 lanes).
    {
        int r = s_selA[wave];
        if (r >= 0) {
            int tr = s_tgt[r];
            if (s_cnt[tr] < BOUNDARY) {
                for (int j = lane; j < BB; j += 64)
                    if (j != r && s_tgt[j] == tr) {
                        int idx = atomicAdd(&s_npA, 1);
                        s_prA[idx] = r; s_pjA[idx] = j;
                    }
            }
        }
        r = s_selB[wave];
        if (r >= 0) {
            int tr = s_tgt[r];
            if (s_cnt[tr] < BOUNDARY) {
                for (int j = lane; j < BB; j += 64)
                    if (j != r && s_tgt[j] == tr) {
                        int idx = atomicAdd(&s_npB, 1);
                        s_prB[idx] = r; s_pjB[idx] = j;
                    }
            }
        }
    }
    __syncthreads();

    // hinge terms: <= 16 pairs per column; wave 0 -> column A, wave 1 -> B
    if (wave < 2) {
        const int   np  = (wave == 0) ? s_npA : s_npB;
        const int*  pr  = (wave == 0) ? s_prA : s_prB;
        const int*  pj  = (wave == 0) ? s_pjA : s_pjB;
        const float* vn = (wave == 0) ? s_vnA : s_vnB;
        float s = 0.f; int c = 0;
        if (lane < np) {
            int r = pr[lane], j = pj[lane];
            const float4* xr = (const float4*)(x + r * DD);
            const float4* xj = (const float4*)(x + j * DD);
            float d0 = 0.f, d1 = 0.f, d2 = 0.f, d3 = 0.f;
            for (int cc = 0; cc < DD / 4; ++cc) {
                float4 a = xr[cc], b = xj[cc];
                d0 += a.x * b.x; d1 += a.y * b.y; d2 += a.z * b.z; d3 += a.w * b.w;
            }
            float dot = (d0 + d1) + (d2 + d3);
            float dsq = fmaxf((s_sq[r] + s_sq[j]) - 2.f * dot, 0.f);
            float dpos = (dsq == 0.f) ? 0.f : sqrtf(dsq);
            float tv = dpos + vn[r] + 1.0f;      // d[r,j] - d[r,col] + margin
            if (tv > 0.f) { s = tv; c = (tv > 1e-7f) ? 1 : 0; }
        }
        for (int off = 32; off > 0; off >>= 1) {
            s += __shfl_down(s, off);
            c += __shfl_down(c, off);
        }
        if (lane == 0) {
            int col = (wave == 0) ? cA : cB;
            partS[col] = s; partC[col] = c;
        }
    }
}

__global__ __launch_bounds__(64) void fin_kernel(
    const float* __restrict__ partS, const int* __restrict__ partC,
    float* __restrict__ out)
{
    int lane = threadIdx.x;              // 0..63; 512 partials = 128 x float4
    const float4* pS = (const float4*)partS;
    const int4*   pC = (const int4*)partC;
    float4 a = pS[lane], b = pS[lane + 64];
    int4   u = pC[lane], v = pC[lane + 64];
    float S = ((a.x + a.y) + (a.z + a.w)) + ((b.x + b.y) + (b.z + b.w));
    int   C = ((u.x + u.y) + (u.z + u.w)) + ((v.x + v.y) + (v.z + v.w));
    for (int off = 32; off > 0; off >>= 1) {
        S += __shfl_down(S, off);
        C += __shfl_down(C, off);
    }
    if (lane == 0) out[0] = S / ((float)C + 1e-7f);
}

extern "C" void kernel_launch(void* const* d_in, const int* in_sizes, int n_in,
                              void* d_out, int out_size, void* d_ws, size_t ws_size,
                              hipStream_t stream) {
    const float* x   = (const float*)d_in[0];
    const int*   tgt = (const int*)d_in[1];
    float* out = (float*)d_out;

    char* ws = (char*)d_ws;
    float* partS = (float*)(ws + 0);
    int*   partC = (int*)(ws + 2048);

    fused2_kernel<<<BB / 2, 512, 0, stream>>>(x, tgt, partS, partC);
    fin_kernel<<<1, 64, 0, stream>>>(partS, partC, out);
}

// Round 5
// 70.428 us; speedup vs baseline: 1.0401x; 1.0401x over previous
//
#include <hip/hip_runtime.h>
#include <math.h>

#define BB 512
#define DD 128
#define KK 8
#define BOUNDARY 4

// ---------------- workspace layout (bytes) ----------------
// partS : 0    .. 2048   (512 float)  per-block loss partial sum
// partC : 2048 .. 4096   (512 int)    per-block hinge count
// Written unconditionally by every block -> no memset needed.
// NO device-scope atomics/fences anywhere (prior session: any single-kernel
// finalize costs 40-60 us of cross-XCD coherence tail; tiny 2nd dispatch wins).
//
// Round history (measured):
//  R1 3-kernel split: +2.8us (extra graph node dominates interior savings)
//  R2 2-launch, predicated top-k pop: 71.50
//  R3 (THIS FILE) + 2-row MLP distance loop: 71.03  <- best
//  R4 2-col/block, grid 256: 73.25 — halved L2 traffic AND parallelized
//     top-k yet LOST -> binding constraint is cross-block phase overlap
//     (2 resident blocks/CU hide each other's serial phases), not L2 BW,
//     not top-k serialization. Grid must stay 512 @ 2 blocks/CU.
// Conclusion: controllable interior ~5-6us of ~71; remaining tweaks attack
// <1us of already-overlapped time. This is the measured optimum structure.
//
// Occupancy curve (measured, prior session): 4 waves/CU = 77.4us, 8 = 73.9,
// 16 = 71.1, 32 = 75.1 -> pin 16 waves/CU (512 thr, __launch_bounds__(512,4)).
//
// Algebraic facts exploited (boundary = int(512/128) = 4):
//  * anchor rows belong to classes with <= 3 members, so the positive top-8
//    selects ALL same-class rows: mask_ap[i][j] == anchors[i] & tgt[j]==tgt[i] & i!=j.
//  * block k owns column k: its neg top-8 rows r are exactly the (i=r, k)
//    entries of mask_an, and d[r,k] = -s_vn[r] (selected negs are always
//    different-class; s_vn holds -d).
//  * the diagonal is never consumed (neg-masked; positives exclude j==r).
//  * the <= 16 positive distances d[r,j] per block are recomputed directly
//    from x (one 128-dim dot each) — hinge values only, not selections.

__global__ __launch_bounds__(512, 4) void fused_kernel(
    const float* __restrict__ x, const int* __restrict__ tgt,
    float* __restrict__ partS, int* __restrict__ partC)
{
    __shared__ float4 xi4[DD / 4];
    __shared__ float s_vn[BB];         // -d, masked to -inf on same-class
    __shared__ float s_sq[BB];         // squared norms of all rows
    __shared__ int   s_tgt[BB];
    __shared__ int   s_cnt[128];       // class histogram
    __shared__ int   s_sel[KK];        // selected neg rows, -1 invalid
    __shared__ int   s_pr[16], s_pj[16];
    __shared__ int   s_np;

    int k = blockIdx.x;
    int t = threadIdx.x;               // 0..511
    if (t < DD / 4) xi4[t] = ((const float4*)(x + k * DD))[t];
    if (t < 128) s_cnt[t] = 0;
    if (t == 0) s_np = 0;
    s_tgt[t] = tgt[t];
    __syncthreads();
    int tk = s_tgt[k];

    float z0 = 0.f, z1 = 0.f, z2 = 0.f, z3 = 0.f;
    for (int c = 0; c < DD / 4; ++c) {
        float4 a = xi4[c];
        z0 += a.x * a.x; z1 += a.y * a.y; z2 += a.z * a.z; z3 += a.w * a.w;
    }
    float sqk = (z0 + z1) + (z2 + z3);

    // distance loop: 8 lanes cooperate per row (coalesced 128-B segments),
    // TWO rows per pass per group: g = t>>3 (0..63), sub = t&7; pass p covers
    // rows p*128+g and p*128+64+g. 8 global float4 loads in flight per lane;
    // a-loads (row-invariant) shared; two shfl chains interleave.
    {
        int g = t >> 3, sub = t & 7;
        for (int pass = 0; pass < 4; ++pass) {
            int r0 = pass * 128 + g;
            int r1 = r0 + 64;
            const float4* xr0 = (const float4*)(x + r0 * DD);
            const float4* xr1 = (const float4*)(x + r1 * DD);
            float4 a0 = xi4[sub], a1 = xi4[sub + 8], a2 = xi4[sub + 16], a3 = xi4[sub + 24];
            float4 p0 = xr0[sub], p1 = xr0[sub + 8], p2 = xr0[sub + 16], p3 = xr0[sub + 24];
            float4 q0 = xr1[sub], q1 = xr1[sub + 8], q2 = xr1[sub + 16], q3 = xr1[sub + 24];

            float dA0 = a0.x*p0.x + a0.y*p0.y + a0.z*p0.z + a0.w*p0.w;
            float sA0 = p0.x*p0.x + p0.y*p0.y + p0.z*p0.z + p0.w*p0.w;
            float dA1 = a1.x*p1.x + a1.y*p1.y + a1.z*p1.z + a1.w*p1.w;
            float sA1 = p1.x*p1.x + p1.y*p1.y + p1.z*p1.z + p1.w*p1.w;
            float dA2 = a2.x*p2.x + a2.y*p2.y + a2.z*p2.z + a2.w*p2.w;
            float sA2 = p2.x*p2.x + p2.y*p2.y + p2.z*p2.z + p2.w*p2.w;
            float dA3 = a3.x*p3.x + a3.y*p3.y + a3.z*p3.z + a3.w*p3.w;
            float sA3 = p3.x*p3.x + p3.y*p3.y + p3.z*p3.z + p3.w*p3.w;

            float dB0 = a0.x*q0.x + a0.y*q0.y + a0.z*q0.z + a0.w*q0.w;
            float sB0 = q0.x*q0.x + q0.y*q0.y + q0.z*q0.z + q0.w*q0.w;
            float dB1 = a1.x*q1.x + a1.y*q1.y + a1.z*q1.z + a1.w*q1.w;
            float sB1 = q1.x*q1.x + q1.y*q1.y + q1.z*q1.z + q1.w*q1.w;
            float dB2 = a2.x*q2.x + a2.y*q2.y + a2.z*q2.z + a2.w*q2.w;
            float sB2 = q2.x*q2.x + q2.y*q2.y + q2.z*q2.z + q2.w*q2.w;
            float dB3 = a3.x*q3.x + a3.y*q3.y + a3.z*q3.z + a3.w*q3.w;
            float sB3 = q3.x*q3.x + q3.y*q3.y + q3.z*q3.z + q3.w*q3.w;

            float dotA = (dA0 + dA1) + (dA2 + dA3);
            float sqA  = (sA0 + sA1) + (sA2 + sA3);
            float dotB = (dB0 + dB1) + (dB2 + dB3);
            float sqB  = (sB0 + sB1) + (sB2 + sB3);
            for (int off = 4; off > 0; off >>= 1) {
                dotA += __shfl_down(dotA, off, 8);
                sqA  += __shfl_down(sqA,  off, 8);
                dotB += __shfl_down(dotB, off, 8);
                sqB  += __shfl_down(sqB,  off, 8);
            }
            if (sub == 0) {
                float dsqA = fmaxf((sqk + sqA) - 2.f * dotA, 0.f);
                float dvA = (dsqA == 0.f) ? 0.f : sqrtf(dsqA);
                s_sq[r0] = sqA;
                s_vn[r0] = (s_tgt[r0] == tk) ? -INFINITY : -dvA;
                float dsqB = fmaxf((sqk + sqB) - 2.f * dotB, 0.f);
                float dvB = (dsqB == 0.f) ? 0.f : sqrtf(dsqB);
                s_sq[r1] = sqB;
                s_vn[r1] = (s_tgt[r1] == tk) ? -INFINITY : -dvB;
            }
        }
    }
    __syncthreads();

    int wave = t >> 6, lane = t & 63;
    if (wave == 0) {
        // neg top-8: largest -d among different-class rows (lax.top_k order:
        // descending value, lower index on tie). Candidates stay in VGPRs:
        // the pop below uses compile-time indices only (no scratch demotion).
        float v[8];
#pragma unroll
        for (int q = 0; q < 8; ++q) v[q] = s_vn[q * 64 + lane];
        for (int pass = 0; pass < KK; ++pass) {
            float bv = -INFINITY; int bq = -1;
#pragma unroll
            for (int q = 0; q < 8; ++q)
                if (v[q] > bv) { bv = v[q]; bq = q; }   // strict > keeps lowest q
            int bi = (bq >= 0) ? (bq * 64 + lane) : (1 << 30);
            for (int off = 32; off > 0; off >>= 1) {
                float ov = __shfl_down(bv, off);
                int   oi = __shfl_down(bi, off);
                if (ov > bv || (ov == bv && oi < bi)) { bv = ov; bi = oi; }
            }
            bv = __shfl(bv, 0); bi = __shfl(bi, 0);
            if (lane == 0) s_sel[pass] = (bv == -INFINITY) ? -1 : bi;
            const int  popq = bi >> 6;
            const bool mine = ((bi & 63) == lane);
#pragma unroll
            for (int q = 0; q < 8; ++q)
                if (mine && q == popq) v[q] = -INFINITY;
        }
    } else if (wave == 1) {
        // class histogram (includes self-counts)
#pragma unroll
        for (int q = 0; q < 8; ++q) atomicAdd(&s_cnt[s_tgt[q * 64 + lane]], 1);
    }
    __syncthreads();

    // collect (anchor r, positive j) pairs: 8 waves, one top-k slot each
    {
        int r = s_sel[wave];
        if (r >= 0) {
            int tr = s_tgt[r];
            if (s_cnt[tr] < BOUNDARY) {          // anchor: class size <= 3
                for (int j = lane; j < BB; j += 64)
                    if (j != r && s_tgt[j] == tr) {
                        int idx = atomicAdd(&s_np, 1);
                        s_pr[idx] = r; s_pj[idx] = j;
                    }
            }
        }
    }
    __syncthreads();

    // hinge terms: <= 16 pairs, all resident in wave 0
    float s = 0.f; int c = 0;
    if (t < s_np) {
        int r = s_pr[t], j = s_pj[t];
        const float4* xr = (const float4*)(x + r * DD);
        const float4* xj = (const float4*)(x + j * DD);
        float d0 = 0.f, d1 = 0.f, d2 = 0.f, d3 = 0.f;
        for (int cc = 0; cc < DD / 4; ++cc) {
            float4 a = xr[cc], b = xj[cc];
            d0 += a.x * b.x; d1 += a.y * b.y; d2 += a.z * b.z; d3 += a.w * b.w;
        }
        float dot = (d0 + d1) + (d2 + d3);
        float dsq = fmaxf((s_sq[r] + s_sq[j]) - 2.f * dot, 0.f);
        float dpos = (dsq == 0.f) ? 0.f : sqrtf(dsq);
        float tv = dpos + s_vn[r] + 1.0f;        // d[r,j] - d[r,k] + margin
        if (tv > 0.f) { s = tv; c = (tv > 1e-7f) ? 1 : 0; }
    }
    if (wave == 0) {
        for (int off = 32; off > 0; off >>= 1) {
            s += __shfl_down(s, off);
            c += __shfl_down(c, off);
        }
        if (lane == 0) { partS[k] = s; partC[k] = c; }
    }
}

__global__ __launch_bounds__(64) void fin_kernel(
    const float* __restrict__ partS, const int* __restrict__ partC,
    float* __restrict__ out)
{
    int lane = threadIdx.x;              // 0..63; 512 partials = 128 x float4
    const float4* pS = (const float4*)partS;
    const int4*   pC = (const int4*)partC;
    float4 a = pS[lane], b = pS[lane + 64];
    int4   u = pC[lane], v = pC[lane + 64];
    float S = ((a.x + a.y) + (a.z + a.w)) + ((b.x + b.y) + (b.z + b.w));
    int   C = ((u.x + u.y) + (u.z + u.w)) + ((v.x + v.y) + (v.z + v.w));
    for (int off = 32; off > 0; off >>= 1) {
        S += __shfl_down(S, off);
        C += __shfl_down(C, off);
    }
    if (lane == 0) out[0] = S / ((float)C + 1e-7f);
}

extern "C" void kernel_launch(void* const* d_in, const int* in_sizes, int n_in,
                              void* d_out, int out_size, void* d_ws, size_t ws_size,
                              hipStream_t stream) {
    const float* x   = (const float*)d_in[0];
    const int*   tgt = (const int*)d_in[1];
    float* out = (float*)d_out;

    char* ws = (char*)d_ws;
    float* partS = (float*)(ws + 0);
    int*   partC = (int*)(ws + 2048);

    fused_kernel<<<BB, 512, 0, stream>>>(x, tgt, partS, partC);
    fin_kernel<<<1, 64, 0, stream>>>(partS, partC, out);
}